// Round 1
// baseline (683.413 us; speedup 1.0000x reference)
//
#include <hip/hip_runtime.h>

#define B_SZ 8
#define N1 8192
#define N2 2048
#define C1 128
#define C2 256
#define CIN 384
#define M0 256
#define NP (B_SZ * N1)   // 65536

typedef __bf16 bf16_t;
typedef bf16_t bf16x8 __attribute__((ext_vector_type(8)));
typedef bf16_t bf16x4 __attribute__((ext_vector_type(4)));
typedef float  f32x4  __attribute__((ext_vector_type(4)));

// ---------------- fp32 -> bf16 weight convert ----------------
__global__ void cvt_bf16_kernel(const float* __restrict__ in, bf16_t* __restrict__ out, int n) {
    int i = blockIdx.x * 256 + threadIdx.x;
    if (i < n) out[i] = (bf16_t)in[i];
}

// ---------------- 3-NN search (per point of xyz1 vs xyz2[batch]) ----------------
// grid: B * (N1/256) blocks of 256 threads; one thread = one query point.
__global__ void nn3_kernel(const float* __restrict__ xyz1, const float* __restrict__ xyz2,
                           int* __restrict__ idx3, float* __restrict__ w3) {
    __shared__ float sx[N2], sy[N2], sz[N2], sn[N2];   // 32 KB
    int b  = blockIdx.x >> 5;           // N1/256 = 32 blocks per batch
    int i0 = (blockIdx.x & 31) << 8;
    const float* x2 = xyz2 + (size_t)b * N2 * 3;
    for (int j = threadIdx.x; j < N2; j += 256) {
        float x = x2[j * 3 + 0], y = x2[j * 3 + 1], z = x2[j * 3 + 2];
        sx[j] = x; sy[j] = y; sz[j] = z; sn[j] = x * x + y * y + z * z;
    }
    __syncthreads();
    int i = i0 + threadIdx.x;
    const float* p = xyz1 + ((size_t)b * N1 + i) * 3;
    float px = p[0], py = p[1], pz = p[2];
    float pn = px * px + py * py + pz * pz;
    float d0 = 1e30f, d1 = 1e30f, d2 = 1e30f;
    int   j0 = 0,     j1 = 0,     j2 = 0;
    for (int j = 0; j < N2; ++j) {
        float dot = px * sx[j] + py * sy[j] + pz * sz[j];
        float sq  = pn + sn[j] - 2.0f * dot;
        float d   = sqrtf(fmaxf(sq, 0.0f));   // match reference: sqrt(clamped sq), stable ties
        if (d < d2) {
            if (d < d1) {
                d2 = d1; j2 = j1;
                if (d < d0) { d1 = d0; j1 = j0; d0 = d; j0 = j; }
                else        { d1 = d;  j1 = j; }
            } else { d2 = d; j2 = j; }
        }
    }
    float inv0 = 1.0f / (d0 + 1e-8f);
    float inv1 = 1.0f / (d1 + 1e-8f);
    float inv2 = 1.0f / (d2 + 1e-8f);
    float s = inv0 + inv1 + inv2;
    size_t o = ((size_t)b * N1 + i) * 3;
    w3[o] = inv0 / s; w3[o + 1] = inv1 / s; w3[o + 2] = inv2 / s;
    idx3[o] = j0; idx3[o + 1] = j1; idx3[o + 2] = j2;
}

// ---------------- gather 3 rows of points2, weighted sum, concat points1 -> X bf16 ----------------
// grid: NP blocks of 128 threads; one block = one point, channels coalesced.
__global__ void gather_kernel(const float* __restrict__ points1, const float* __restrict__ points2,
                              const int* __restrict__ idx3, const float* __restrict__ w3,
                              bf16_t* __restrict__ X) {
    int p = blockIdx.x;
    int b = p >> 13;   // /8192
    const int*   id = idx3 + (size_t)p * 3;
    const float* w  = w3  + (size_t)p * 3;
    int   i0 = id[0], i1 = id[1], i2 = id[2];
    float w0 = w[0],  w1 = w[1],  w2 = w[2];
    const float* P2 = points2 + (size_t)b * N2 * C2;
    const float* r0 = P2 + (size_t)i0 * C2;
    const float* r1 = P2 + (size_t)i1 * C2;
    const float* r2 = P2 + (size_t)i2 * C2;
    bf16_t* Xr = X + (size_t)p * CIN;
    int t = threadIdx.x;
#pragma unroll
    for (int k = 0; k < 2; ++k) {
        int c = t + k * 128;
        float v = w0 * r0[c] + w1 * r1[c] + w2 * r2[c];
        Xr[c] = (bf16_t)v;
    }
    const float* p1 = points1 + (size_t)p * C1;
    Xr[C2 + t] = (bf16_t)p1[t];
}

// ---------------- bf16 MFMA GEMM: H[p][o] = sum_k A[p][k] * Wt[o][k] ----------------
// A: (NP x K) row-major bf16. Wt: (256 x K) row-major bf16 (== B^T, k-contiguous).
// block = 256 thr = 4 waves (2x2); block tile 128x128; wave tile 64x64 (4x4 MFMA 16x16x32).
__global__ __launch_bounds__(256) void gemm_kernel(const bf16_t* __restrict__ A,
                                                   const bf16_t* __restrict__ Wt,
                                                   float* __restrict__ H, int K) {
    int wave = threadIdx.x >> 6;
    int lane = threadIdx.x & 63;
    int wr = wave >> 1, wc = wave & 1;
    int row0 = blockIdx.x * 128 + wr * 64;
    int col0 = blockIdx.y * 128 + wc * 64;
    int l15  = lane & 15;
    int quad = lane >> 4;
    f32x4 acc[4][4] = {};
    const bf16_t* Ap = A  + ((size_t)row0 + l15) * K + quad * 8;
    const bf16_t* Wp = Wt + ((size_t)col0 + l15) * K + quad * 8;
    for (int k0 = 0; k0 < K; k0 += 32) {
        bf16x8 a[4], bfr[4];
#pragma unroll
        for (int i = 0; i < 4; ++i) a[i]   = *(const bf16x8*)(Ap + (size_t)i * 16 * K + k0);
#pragma unroll
        for (int i = 0; i < 4; ++i) bfr[i] = *(const bf16x8*)(Wp + (size_t)i * 16 * K + k0);
#pragma unroll
        for (int mi = 0; mi < 4; ++mi)
#pragma unroll
            for (int ni = 0; ni < 4; ++ni)
                acc[mi][ni] = __builtin_amdgcn_mfma_f32_16x16x32_bf16(a[mi], bfr[ni], acc[mi][ni], 0, 0, 0);
    }
    // C/D layout (verified m89): col = lane&15, row = quad*4 + reg
#pragma unroll
    for (int mi = 0; mi < 4; ++mi)
#pragma unroll
        for (int ni = 0; ni < 4; ++ni) {
            int col  = col0 + ni * 16 + l15;
            int rowb = row0 + mi * 16 + quad * 4;
#pragma unroll
            for (int r = 0; r < 4; ++r)
                H[(size_t)(rowb + r) * 256 + col] = acc[mi][ni][r];
        }
}

// ---------------- per-channel sum / sumsq over rows ----------------
// grid: 1024 blocks of 256 thr; block handles 64 rows, thread t = channel t.
__global__ void colstats_kernel(const float* __restrict__ H, float* __restrict__ sum,
                                float* __restrict__ sumsq) {
    int c = threadIdx.x;
    size_t r0 = (size_t)blockIdx.x * 64;
    float s = 0.0f, ss = 0.0f;
    for (int r = 0; r < 64; ++r) {
        float v = H[(r0 + r) * 256 + c];
        s += v;
        ss = fmaf(v, v, ss);
    }
    atomicAdd(&sum[c], s);
    atomicAdd(&sumsq[c], ss);
}

// ---------------- BN stats -> scale/shift ----------------
__global__ void finalize_kernel(const float* __restrict__ sum, const float* __restrict__ sumsq,
                                const float* __restrict__ gamma, const float* __restrict__ beta,
                                float* __restrict__ scale, float* __restrict__ shift) {
    int c = threadIdx.x;
    float m   = sum[c]   * (1.0f / NP);
    float var = sumsq[c] * (1.0f / NP) - m * m;
    float sc  = rsqrtf(var + 1e-5f) * gamma[c];
    scale[c] = sc;
    shift[c] = fmaf(-m, sc, beta[c]);
}

// ---------------- BN+ReLU, fp32 in -> bf16 out (feeds GEMM2) ----------------
__global__ void bnrelu_bf16_kernel(const float* __restrict__ H, const float* __restrict__ scale,
                                   const float* __restrict__ shift, bf16_t* __restrict__ out) {
    int tid = blockIdx.x * 256 + threadIdx.x;
    float4 v = ((const float4*)H)[tid];
    int c = (tid & 63) * 4;
    bf16x4 o;
    o[0] = (bf16_t)fmaxf(fmaf(v.x, scale[c + 0], shift[c + 0]), 0.0f);
    o[1] = (bf16_t)fmaxf(fmaf(v.y, scale[c + 1], shift[c + 1]), 0.0f);
    o[2] = (bf16_t)fmaxf(fmaf(v.z, scale[c + 2], shift[c + 2]), 0.0f);
    o[3] = (bf16_t)fmaxf(fmaf(v.w, scale[c + 3], shift[c + 3]), 0.0f);
    *(bf16x4*)(out + (size_t)tid * 4) = o;
}

// ---------------- BN+ReLU, fp32 in-place (final output) ----------------
__global__ void bnrelu_f32_kernel(float* __restrict__ H, const float* __restrict__ scale,
                                  const float* __restrict__ shift) {
    int tid = blockIdx.x * 256 + threadIdx.x;
    float4 v = ((float4*)H)[tid];
    int c = (tid & 63) * 4;
    float4 o;
    o.x = fmaxf(fmaf(v.x, scale[c + 0], shift[c + 0]), 0.0f);
    o.y = fmaxf(fmaf(v.y, scale[c + 1], shift[c + 1]), 0.0f);
    o.z = fmaxf(fmaf(v.z, scale[c + 2], shift[c + 2]), 0.0f);
    o.w = fmaxf(fmaf(v.w, scale[c + 3], shift[c + 3]), 0.0f);
    ((float4*)H)[tid] = o;
}

extern "C" void kernel_launch(void* const* d_in, const int* in_sizes, int n_in,
                              void* d_out, int out_size, void* d_ws, size_t ws_size,
                              hipStream_t stream) {
    const float* xyz1    = (const float*)d_in[0];
    const float* xyz2    = (const float*)d_in[1];
    const float* points1 = (const float*)d_in[2];
    const float* points2 = (const float*)d_in[3];
    const float* W0      = (const float*)d_in[4];
    const float* g0      = (const float*)d_in[5];
    const float* b0      = (const float*)d_in[6];
    const float* W1      = (const float*)d_in[7];
    const float* g1      = (const float*)d_in[8];
    const float* b1      = (const float*)d_in[9];
    float* out = (float*)d_out;

    // ws layout (float offsets)
    float* wsf    = (float*)d_ws;
    float* s0     = wsf + 0;
    float* ss0    = wsf + 256;
    float* s1     = wsf + 512;
    float* ss1    = wsf + 768;
    float* scale0 = wsf + 1024;
    float* shift0 = wsf + 1280;
    float* scale1 = wsf + 1536;
    float* shift1 = wsf + 1792;
    float* w3     = wsf + 2048;                       // 196608 f
    int*   idx3   = (int*)(wsf + 198656);             // 196608 i
    bf16_t* Wb0   = (bf16_t*)(wsf + 395264);          // 98304 bf16
    bf16_t* Wb1   = (bf16_t*)(wsf + 444416);          // 65536 bf16
    bf16_t* X     = (bf16_t*)(wsf + 477184);          // NP*384 bf16
    bf16_t* X1    = (bf16_t*)(wsf + 13060096);        // NP*256 bf16
    // total ~86 MB

    hipMemsetAsync(wsf, 0, 1024 * sizeof(float), stream);   // zero stat accumulators

    cvt_bf16_kernel<<<(M0 * CIN + 255) / 256, 256, 0, stream>>>(W0, Wb0, M0 * CIN);
    cvt_bf16_kernel<<<(M0 * M0 + 255) / 256, 256, 0, stream>>>(W1, Wb1, M0 * M0);

    nn3_kernel<<<B_SZ * (N1 / 256), 256, 0, stream>>>(xyz1, xyz2, idx3, w3);
    gather_kernel<<<NP, 128, 0, stream>>>(points1, points2, idx3, w3, X);

    // layer 0: GEMM -> d_out (fp32 scratch), stats, normalize -> X1 (bf16)
    gemm_kernel<<<dim3(NP / 128, 2), 256, 0, stream>>>(X, Wb0, out, CIN);
    colstats_kernel<<<1024, 256, 0, stream>>>(out, s0, ss0);
    finalize_kernel<<<1, 256, 0, stream>>>(s0, ss0, g0, b0, scale0, shift0);
    bnrelu_bf16_kernel<<<NP / 4, 256, 0, stream>>>(out, scale0, shift0, X1);

    // layer 1: GEMM -> d_out, stats, normalize in place
    gemm_kernel<<<dim3(NP / 128, 2), 256, 0, stream>>>(X1, Wb1, out, M0);
    colstats_kernel<<<1024, 256, 0, stream>>>(out, s1, ss1);
    finalize_kernel<<<1, 256, 0, stream>>>(s1, ss1, g1, b1, scale1, shift1);
    bnrelu_f32_kernel<<<NP / 4, 256, 0, stream>>>(out, scale1, shift1);
}

// Round 2
// 410.640 us; speedup vs baseline: 1.6643x; 1.6643x over previous
//
#include <hip/hip_runtime.h>

#define B_SZ 8
#define N1 8192
#define N2 2048
#define C1 128
#define C2 256
#define CIN 384
#define M0 256
#define NP (B_SZ * N1)   // 65536
#define CHUNKS 8
#define CHUNK (N2 / CHUNKS)   // 256

typedef __bf16 bf16_t;
typedef bf16_t bf16x8 __attribute__((ext_vector_type(8)));
typedef bf16_t bf16x4 __attribute__((ext_vector_type(4)));
typedef float  f32x4  __attribute__((ext_vector_type(4)));

// ---------------- fp32 -> bf16 weight convert ----------------
__global__ void cvt_bf16_kernel(const float* __restrict__ in, bf16_t* __restrict__ out, int n) {
    int i = blockIdx.x * 256 + threadIdx.x;
    if (i < n) out[i] = (bf16_t)in[i];
}

// ---------------- 3-NN partial: each block = 256 queries x one 256-candidate chunk --------
// grid: dim3(B*N1/256, CHUNKS) = 2048 blocks -> 8 blocks/CU, 32 waves/CU (latency hiding).
__global__ __launch_bounds__(256) void nn3_partial_kernel(const float* __restrict__ xyz1,
                                                          const float* __restrict__ xyz2,
                                                          float* __restrict__ pd,
                                                          int* __restrict__ pi) {
    __shared__ float4 s2[CHUNK];   // 4 KB: x,y,z,|p|^2
    int b = blockIdx.x >> 5;                 // 32 blocks per batch
    int i = ((blockIdx.x & 31) << 8) + threadIdx.x;
    int c = blockIdx.y;
    const float* x2 = xyz2 + ((size_t)b * N2 + (size_t)c * CHUNK) * 3;
    {
        int j = threadIdx.x;                 // CHUNK == blockDim
        float x = x2[j * 3 + 0], y = x2[j * 3 + 1], z = x2[j * 3 + 2];
        s2[j] = make_float4(x, y, z, x * x + y * y + z * z);
    }
    __syncthreads();
    const float* p = xyz1 + ((size_t)b * N1 + i) * 3;
    float px = p[0], py = p[1], pz = p[2];
    float pn = px * px + py * py + pz * pz;
    float d0 = 1e30f, d1 = 1e30f, d2 = 1e30f;
    int   j0 = 0,     j1 = 0,     j2 = 0;
#pragma unroll 4
    for (int j = 0; j < CHUNK; ++j) {
        float4 v = s2[j];
        float dot = px * v.x + py * v.y + pz * v.z;
        float sq  = pn + v.w - 2.0f * dot;
        float d   = sqrtf(fmaxf(sq, 0.0f));   // match reference exactly (stable ties)
        if (d < d2) {
            if (d < d1) {
                d2 = d1; j2 = j1;
                if (d < d0) { d1 = d0; j1 = j0; d0 = d; j0 = j; }
                else        { d1 = d;  j1 = j; }
            } else { d2 = d; j2 = j; }
        }
    }
    int jb = c * CHUNK;
    size_t o = (((size_t)b * N1 + i) * CHUNKS + (size_t)c) * 3;
    pd[o] = d0; pd[o + 1] = d1; pd[o + 2] = d2;
    pi[o] = j0 + jb; pi[o + 1] = j1 + jb; pi[o + 2] = j2 + jb;
}

// ---------------- merge 8 partial top-3 lists -> final idx3 / w3 ----------------
// Scan in chunk-major order == global index order; strict < keeps earliest (stable ties).
__global__ void nn3_merge_kernel(const float* __restrict__ pd, const int* __restrict__ pi,
                                 int* __restrict__ idx3, float* __restrict__ w3) {
    int p = blockIdx.x * 256 + threadIdx.x;
    const float* dp = pd + (size_t)p * (CHUNKS * 3);
    const int*   ip = pi + (size_t)p * (CHUNKS * 3);
    float d0 = 1e30f, d1 = 1e30f, d2 = 1e30f;
    int   j0 = 0,     j1 = 0,     j2 = 0;
#pragma unroll
    for (int k = 0; k < CHUNKS * 3; ++k) {
        float d = dp[k];
        int   j = ip[k];
        if (d < d2) {
            if (d < d1) {
                d2 = d1; j2 = j1;
                if (d < d0) { d1 = d0; j1 = j0; d0 = d; j0 = j; }
                else        { d1 = d;  j1 = j; }
            } else { d2 = d; j2 = j; }
        }
    }
    float inv0 = 1.0f / (d0 + 1e-8f);
    float inv1 = 1.0f / (d1 + 1e-8f);
    float inv2 = 1.0f / (d2 + 1e-8f);
    float s = inv0 + inv1 + inv2;
    size_t o = (size_t)p * 3;
    w3[o] = inv0 / s; w3[o + 1] = inv1 / s; w3[o + 2] = inv2 / s;
    idx3[o] = j0; idx3[o + 1] = j1; idx3[o + 2] = j2;
}

// ---------------- gather 3 rows of points2, weighted sum, concat points1 -> X bf16 ----------------
__global__ void gather_kernel(const float* __restrict__ points1, const float* __restrict__ points2,
                              const int* __restrict__ idx3, const float* __restrict__ w3,
                              bf16_t* __restrict__ X) {
    int p = blockIdx.x;
    int b = p >> 13;   // /8192
    const int*   id = idx3 + (size_t)p * 3;
    const float* w  = w3  + (size_t)p * 3;
    int   i0 = id[0], i1 = id[1], i2 = id[2];
    float w0 = w[0],  w1 = w[1],  w2 = w[2];
    const float* P2 = points2 + (size_t)b * N2 * C2;
    const float* r0 = P2 + (size_t)i0 * C2;
    const float* r1 = P2 + (size_t)i1 * C2;
    const float* r2 = P2 + (size_t)i2 * C2;
    bf16_t* Xr = X + (size_t)p * CIN;
    int t = threadIdx.x;
#pragma unroll
    for (int k = 0; k < 2; ++k) {
        int c = t + k * 128;
        float v = w0 * r0[c] + w1 * r1[c] + w2 * r2[c];
        Xr[c] = (bf16_t)v;
    }
    const float* p1 = points1 + (size_t)p * C1;
    Xr[C2 + t] = (bf16_t)p1[t];
}

// ---------------- bf16 MFMA GEMM + fused column stats ----------------
// A: (NP x K) bf16 row-major. Wt: (256 x K) bf16 row-major (k-contiguous).
// block = 256 thr = 4 waves (2x2); block tile 128x128; wave tile 64x64 (4x4 MFMA 16x16x32).
__global__ __launch_bounds__(256) void gemm_kernel(const bf16_t* __restrict__ A,
                                                   const bf16_t* __restrict__ Wt,
                                                   float* __restrict__ H, int K,
                                                   float* __restrict__ sum,
                                                   float* __restrict__ sumsq) {
    int wave = threadIdx.x >> 6;
    int lane = threadIdx.x & 63;
    int wr = wave >> 1, wc = wave & 1;
    int row0 = blockIdx.x * 128 + wr * 64;
    int col0 = blockIdx.y * 128 + wc * 64;
    int l15  = lane & 15;
    int quad = lane >> 4;
    f32x4 acc[4][4] = {};
    const bf16_t* Ap = A  + ((size_t)row0 + l15) * K + quad * 8;
    const bf16_t* Wp = Wt + ((size_t)col0 + l15) * K + quad * 8;
    for (int k0 = 0; k0 < K; k0 += 32) {
        bf16x8 a[4], bfr[4];
#pragma unroll
        for (int i = 0; i < 4; ++i) a[i]   = *(const bf16x8*)(Ap + (size_t)i * 16 * K + k0);
#pragma unroll
        for (int i = 0; i < 4; ++i) bfr[i] = *(const bf16x8*)(Wp + (size_t)i * 16 * K + k0);
#pragma unroll
        for (int mi = 0; mi < 4; ++mi)
#pragma unroll
            for (int ni = 0; ni < 4; ++ni)
                acc[mi][ni] = __builtin_amdgcn_mfma_f32_16x16x32_bf16(a[mi], bfr[ni], acc[mi][ni], 0, 0, 0);
    }
    // C/D layout (verified m89): col = lane&15, row = quad*4 + reg
#pragma unroll
    for (int mi = 0; mi < 4; ++mi)
#pragma unroll
        for (int ni = 0; ni < 4; ++ni) {
            int col  = col0 + ni * 16 + l15;
            int rowb = row0 + mi * 16 + quad * 4;
#pragma unroll
            for (int r = 0; r < 4; ++r)
                H[(size_t)(rowb + r) * 256 + col] = acc[mi][ni][r];
        }
    // ---- fused per-column sum / sumsq over this block's 128x128 tile ----
    __shared__ float lsum[128], lssq[128];
    if (threadIdx.x < 128) { lsum[threadIdx.x] = 0.0f; lssq[threadIdx.x] = 0.0f; }
    __syncthreads();
#pragma unroll
    for (int ni = 0; ni < 4; ++ni) {
        float s = 0.0f, ss = 0.0f;
#pragma unroll
        for (int mi = 0; mi < 4; ++mi)
#pragma unroll
            for (int r = 0; r < 4; ++r) {
                float v = acc[mi][ni][r];
                s += v; ss = fmaf(v, v, ss);
            }
        // reduce the 4 quads (same column) within the wave
        s  += __shfl_xor(s, 16);  s  += __shfl_xor(s, 32);
        ss += __shfl_xor(ss, 16); ss += __shfl_xor(ss, 32);
        if (quad == 0) {
            int cl = wc * 64 + ni * 16 + l15;
            atomicAdd(&lsum[cl], s);
            atomicAdd(&lssq[cl], ss);
        }
    }
    __syncthreads();
    if (threadIdx.x < 128) {
        int col = blockIdx.y * 128 + threadIdx.x;
        atomicAdd(&sum[col],   lsum[threadIdx.x]);
        atomicAdd(&sumsq[col], lssq[threadIdx.x]);
    }
}

// ---------------- BN stats -> scale/shift ----------------
__global__ void finalize_kernel(const float* __restrict__ sum, const float* __restrict__ sumsq,
                                const float* __restrict__ gamma, const float* __restrict__ beta,
                                float* __restrict__ scale, float* __restrict__ shift) {
    int c = threadIdx.x;
    float m   = sum[c]   * (1.0f / NP);
    float var = sumsq[c] * (1.0f / NP) - m * m;
    float sc  = rsqrtf(var + 1e-5f) * gamma[c];
    scale[c] = sc;
    shift[c] = fmaf(-m, sc, beta[c]);
}

// ---------------- BN+ReLU, fp32 in -> bf16 out (feeds GEMM2) ----------------
__global__ void bnrelu_bf16_kernel(const float* __restrict__ H, const float* __restrict__ scale,
                                   const float* __restrict__ shift, bf16_t* __restrict__ out) {
    int tid = blockIdx.x * 256 + threadIdx.x;
    float4 v = ((const float4*)H)[tid];
    int c = (tid & 63) * 4;
    bf16x4 o;
    o[0] = (bf16_t)fmaxf(fmaf(v.x, scale[c + 0], shift[c + 0]), 0.0f);
    o[1] = (bf16_t)fmaxf(fmaf(v.y, scale[c + 1], shift[c + 1]), 0.0f);
    o[2] = (bf16_t)fmaxf(fmaf(v.z, scale[c + 2], shift[c + 2]), 0.0f);
    o[3] = (bf16_t)fmaxf(fmaf(v.w, scale[c + 3], shift[c + 3]), 0.0f);
    *(bf16x4*)(out + (size_t)tid * 4) = o;
}

// ---------------- BN+ReLU, fp32 in-place (final output) ----------------
__global__ void bnrelu_f32_kernel(float* __restrict__ H, const float* __restrict__ scale,
                                  const float* __restrict__ shift) {
    int tid = blockIdx.x * 256 + threadIdx.x;
    float4 v = ((float4*)H)[tid];
    int c = (tid & 63) * 4;
    float4 o;
    o.x = fmaxf(fmaf(v.x, scale[c + 0], shift[c + 0]), 0.0f);
    o.y = fmaxf(fmaf(v.y, scale[c + 1], shift[c + 1]), 0.0f);
    o.z = fmaxf(fmaf(v.z, scale[c + 2], shift[c + 2]), 0.0f);
    o.w = fmaxf(fmaf(v.w, scale[c + 3], shift[c + 3]), 0.0f);
    ((float4*)H)[tid] = o;
}

extern "C" void kernel_launch(void* const* d_in, const int* in_sizes, int n_in,
                              void* d_out, int out_size, void* d_ws, size_t ws_size,
                              hipStream_t stream) {
    const float* xyz1    = (const float*)d_in[0];
    const float* xyz2    = (const float*)d_in[1];
    const float* points1 = (const float*)d_in[2];
    const float* points2 = (const float*)d_in[3];
    const float* W0      = (const float*)d_in[4];
    const float* g0      = (const float*)d_in[5];
    const float* b0      = (const float*)d_in[6];
    const float* W1      = (const float*)d_in[7];
    const float* g1      = (const float*)d_in[8];
    const float* b1      = (const float*)d_in[9];
    float* out = (float*)d_out;

    // ws layout (float offsets)
    float* wsf    = (float*)d_ws;
    float* s0     = wsf + 0;
    float* ss0    = wsf + 256;
    float* s1     = wsf + 512;
    float* ss1    = wsf + 768;
    float* scale0 = wsf + 1024;
    float* shift0 = wsf + 1280;
    float* scale1 = wsf + 1536;
    float* shift1 = wsf + 1792;
    float* w3     = wsf + 2048;                       // 196608 f
    int*   idx3   = (int*)(wsf + 198656);             // 196608 i
    bf16_t* Wb0   = (bf16_t*)(wsf + 395264);          // 98304 bf16
    bf16_t* Wb1   = (bf16_t*)(wsf + 444416);          // 65536 bf16
    bf16_t* X     = (bf16_t*)(wsf + 477184);          // NP*384 bf16 (12582912 f)
    // pd/pi alias the X region: consumed by merge BEFORE gather writes X
    float* pd     = wsf + 477184;                     // NP*24 f  (1572864 f)
    int*   pi     = (int*)(wsf + 2050048);            // NP*24 i
    bf16_t* X1    = (bf16_t*)(wsf + 13060096);        // NP*256 bf16
    // total ~86 MB

    hipMemsetAsync(wsf, 0, 1024 * sizeof(float), stream);   // zero stat accumulators

    cvt_bf16_kernel<<<(M0 * CIN + 255) / 256, 256, 0, stream>>>(W0, Wb0, M0 * CIN);
    cvt_bf16_kernel<<<(M0 * M0 + 255) / 256, 256, 0, stream>>>(W1, Wb1, M0 * M0);

    nn3_partial_kernel<<<dim3(B_SZ * (N1 / 256), CHUNKS), 256, 0, stream>>>(xyz1, xyz2, pd, pi);
    nn3_merge_kernel<<<NP / 256, 256, 0, stream>>>(pd, pi, idx3, w3);
    gather_kernel<<<NP, 128, 0, stream>>>(points1, points2, idx3, w3, X);

    // layer 0: GEMM (+stats) -> d_out (fp32 scratch), finalize, normalize -> X1 (bf16)
    gemm_kernel<<<dim3(NP / 128, 2), 256, 0, stream>>>(X, Wb0, out, CIN, s0, ss0);
    finalize_kernel<<<1, 256, 0, stream>>>(s0, ss0, g0, b0, scale0, shift0);
    bnrelu_bf16_kernel<<<NP / 4, 256, 0, stream>>>(out, scale0, shift0, X1);

    // layer 1: GEMM (+stats) -> d_out, finalize, normalize in place
    gemm_kernel<<<dim3(NP / 128, 2), 256, 0, stream>>>(X1, Wb1, out, M0, s1, ss1);
    finalize_kernel<<<1, 256, 0, stream>>>(s1, ss1, g1, b1, scale1, shift1);
    bnrelu_f32_kernel<<<NP / 4, 256, 0, stream>>>(out, scale1, shift1);
}

// Round 3
// 372.445 us; speedup vs baseline: 1.8349x; 1.1026x over previous
//
#include <hip/hip_runtime.h>

#define B_SZ 8
#define N1 8192
#define N2 2048
#define C1 128
#define C2 256
#define CIN 384
#define M0 256
#define NP (B_SZ * N1)   // 65536
#define CHUNKS 8
#define CHUNK (N2 / CHUNKS)   // 256

typedef __bf16 bf16_t;
typedef bf16_t bf16x8 __attribute__((ext_vector_type(8)));
typedef bf16_t bf16x4 __attribute__((ext_vector_type(4)));
typedef bf16_t bf16x2 __attribute__((ext_vector_type(2)));
typedef float  f32x4  __attribute__((ext_vector_type(4)));

// ---------------- fp32 -> bf16 weight convert ----------------
__global__ void cvt_bf16_kernel(const float* __restrict__ in, bf16_t* __restrict__ out, int n) {
    int i = blockIdx.x * 256 + threadIdx.x;
    if (i < n) out[i] = (bf16_t)in[i];
}

// ---------------- 3-NN partial, BRANCHLESS top-3 insertion ----------------
// grid: dim3(B*N1/256, CHUNKS) = 2048 blocks; block = 256 queries x 256-candidate chunk.
__global__ __launch_bounds__(256) void nn3_partial_kernel(const float* __restrict__ xyz1,
                                                          const float* __restrict__ xyz2,
                                                          float* __restrict__ pd,
                                                          int* __restrict__ pi) {
    __shared__ float4 s2[CHUNK];   // 4 KB: x,y,z,|p|^2
    int b = blockIdx.x >> 5;
    int i = ((blockIdx.x & 31) << 8) + threadIdx.x;
    int c = blockIdx.y;
    const float* x2 = xyz2 + ((size_t)b * N2 + (size_t)c * CHUNK) * 3;
    {
        int j = threadIdx.x;
        float x = x2[j * 3 + 0], y = x2[j * 3 + 1], z = x2[j * 3 + 2];
        s2[j] = make_float4(x, y, z, x * x + y * y + z * z);
    }
    __syncthreads();
    const float* p = xyz1 + ((size_t)b * N1 + i) * 3;
    float px = p[0], py = p[1], pz = p[2];
    float pn = px * px + py * py + pz * pz;
    float d0 = 1e30f, d1 = 1e30f, d2 = 1e30f;
    int   j0 = 0,     j1 = 0,     j2 = 0;
#pragma unroll 4
    for (int j = 0; j < CHUNK; ++j) {
        float4 v = s2[j];
        float dot = fmaf(px, v.x, fmaf(py, v.y, pz * v.z));
        float sq  = fmaf(-2.0f, dot, pn + v.w);
        float d   = sqrtf(fmaxf(sq, 0.0f));   // match reference exactly (stable ties)
        bool c0 = d < d0, c1 = d < d1, c2 = d < d2;
        d2 = c1 ? d1 : (c2 ? d : d2);
        j2 = c1 ? j1 : (c2 ? j : j2);
        d1 = c0 ? d0 : (c1 ? d : d1);
        j1 = c0 ? j0 : (c1 ? j : j1);
        d0 = c0 ? d : d0;
        j0 = c0 ? j : j0;
    }
    int jb = c * CHUNK;
    size_t o = (((size_t)b * N1 + i) * CHUNKS + (size_t)c) * 3;
    pd[o] = d0; pd[o + 1] = d1; pd[o + 2] = d2;
    pi[o] = j0 + jb; pi[o + 1] = j1 + jb; pi[o + 2] = j2 + jb;
}

// ---------------- merge 8 partial top-3 lists (chunk-major == index order) ----------------
__global__ void nn3_merge_kernel(const float* __restrict__ pd, const int* __restrict__ pi,
                                 int* __restrict__ idx3, float* __restrict__ w3) {
    int p = blockIdx.x * 256 + threadIdx.x;
    const float* dp = pd + (size_t)p * (CHUNKS * 3);
    const int*   ip = pi + (size_t)p * (CHUNKS * 3);
    float d0 = 1e30f, d1 = 1e30f, d2 = 1e30f;
    int   j0 = 0,     j1 = 0,     j2 = 0;
#pragma unroll
    for (int k = 0; k < CHUNKS * 3; ++k) {
        float d = dp[k];
        int   j = ip[k];
        bool c0 = d < d0, c1 = d < d1, c2 = d < d2;
        d2 = c1 ? d1 : (c2 ? d : d2);
        j2 = c1 ? j1 : (c2 ? j : j2);
        d1 = c0 ? d0 : (c1 ? d : d1);
        j1 = c0 ? j0 : (c1 ? j : j1);
        d0 = c0 ? d : d0;
        j0 = c0 ? j : j0;
    }
    float inv0 = 1.0f / (d0 + 1e-8f);
    float inv1 = 1.0f / (d1 + 1e-8f);
    float inv2 = 1.0f / (d2 + 1e-8f);
    float s = inv0 + inv1 + inv2;
    size_t o = (size_t)p * 3;
    w3[o] = inv0 / s; w3[o + 1] = inv1 / s; w3[o + 2] = inv2 / s;
    idx3[o] = j0; idx3[o + 1] = j1; idx3[o + 2] = j2;
}

// ---------------- gather + weighted sum + concat -> X bf16 (vectorized) ----------------
// block = 128 thr = one point. t<64: interp channels 4t..4t+3; t>=64: points1 channels 2(t-64)..+1
__global__ void gather_kernel(const float* __restrict__ points1, const float* __restrict__ points2,
                              const int* __restrict__ idx3, const float* __restrict__ w3,
                              bf16_t* __restrict__ X) {
    int p = blockIdx.x;
    int b = p >> 13;
    const int*   id = idx3 + (size_t)p * 3;
    const float* w  = w3  + (size_t)p * 3;
    int   i0 = id[0], i1 = id[1], i2 = id[2];
    float w0 = w[0],  w1 = w[1],  w2 = w[2];
    const float* P2 = points2 + (size_t)b * N2 * C2;
    bf16_t* Xr = X + (size_t)p * CIN;
    int t = threadIdx.x;
    if (t < 64) {
        int c = t * 4;
        float4 a = *(const float4*)(P2 + (size_t)i0 * C2 + c);
        float4 bb = *(const float4*)(P2 + (size_t)i1 * C2 + c);
        float4 cc = *(const float4*)(P2 + (size_t)i2 * C2 + c);
        bf16x4 o;
        o[0] = (bf16_t)(w0 * a.x + w1 * bb.x + w2 * cc.x);
        o[1] = (bf16_t)(w0 * a.y + w1 * bb.y + w2 * cc.y);
        o[2] = (bf16_t)(w0 * a.z + w1 * bb.z + w2 * cc.z);
        o[3] = (bf16_t)(w0 * a.w + w1 * bb.w + w2 * cc.w);
        *(bf16x4*)(Xr + c) = o;
    } else {
        int c = (t - 64) * 2;
        float2 v = *(const float2*)(points1 + (size_t)p * C1 + c);
        bf16x2 o;
        o[0] = (bf16_t)v.x; o[1] = (bf16_t)v.y;
        *(bf16x2*)(Xr + C2 + c) = o;
    }
}

// ---------------- GEMM1: X(NP x 384) * W0^T -> H0 bf16 (NP x 256) + column stats ----------------
// 512 thr = 8 waves (2 row x 4 col), block tile 128x256, wave tile 64x64.
__global__ __launch_bounds__(512) void gemm1_kernel(const bf16_t* __restrict__ A,
                                                    const bf16_t* __restrict__ Wt,
                                                    bf16_t* __restrict__ H,
                                                    float* __restrict__ sum,
                                                    float* __restrict__ sumsq) {
    const int K = CIN;
    int wave = threadIdx.x >> 6;
    int lane = threadIdx.x & 63;
    int wr = wave >> 2, wc = wave & 3;
    int row0 = blockIdx.x * 128 + wr * 64;
    int col0 = wc * 64;
    int l15  = lane & 15;
    int quad = lane >> 4;
    f32x4 acc[4][4] = {};
    const bf16_t* Ap = A  + ((size_t)row0 + l15) * K + quad * 8;
    const bf16_t* Wp = Wt + ((size_t)col0 + l15) * K + quad * 8;
    for (int k0 = 0; k0 < K; k0 += 32) {
        bf16x8 a[4], bfr[4];
#pragma unroll
        for (int i = 0; i < 4; ++i) a[i]   = *(const bf16x8*)(Ap + (size_t)i * 16 * K + k0);
#pragma unroll
        for (int i = 0; i < 4; ++i) bfr[i] = *(const bf16x8*)(Wp + (size_t)i * 16 * K + k0);
#pragma unroll
        for (int mi = 0; mi < 4; ++mi)
#pragma unroll
            for (int ni = 0; ni < 4; ++ni)
                acc[mi][ni] = __builtin_amdgcn_mfma_f32_16x16x32_bf16(a[mi], bfr[ni], acc[mi][ni], 0, 0, 0);
    }
    // store bf16 H + stats. C/D layout: col = lane&15, row = quad*4 + reg.
#pragma unroll
    for (int mi = 0; mi < 4; ++mi)
#pragma unroll
        for (int ni = 0; ni < 4; ++ni) {
            int col  = col0 + ni * 16 + l15;
            int rowb = row0 + mi * 16 + quad * 4;
#pragma unroll
            for (int r = 0; r < 4; ++r)
                H[(size_t)(rowb + r) * 256 + col] = (bf16_t)acc[mi][ni][r];
        }
    __shared__ float lsum[256], lssq[256];
    if (threadIdx.x < 256) { lsum[threadIdx.x] = 0.0f; lssq[threadIdx.x] = 0.0f; }
    __syncthreads();
#pragma unroll
    for (int ni = 0; ni < 4; ++ni) {
        float s = 0.0f, ss = 0.0f;
#pragma unroll
        for (int mi = 0; mi < 4; ++mi)
#pragma unroll
            for (int r = 0; r < 4; ++r) {
                float v = acc[mi][ni][r];
                s += v; ss = fmaf(v, v, ss);
            }
        s  += __shfl_xor(s, 16);  s  += __shfl_xor(s, 32);
        ss += __shfl_xor(ss, 16); ss += __shfl_xor(ss, 32);
        if (quad == 0) {
            int cl = col0 + ni * 16 + l15;
            atomicAdd(&lsum[cl], s);
            atomicAdd(&lssq[cl], ss);
        }
    }
    __syncthreads();
    if (threadIdx.x < 256) {
        atomicAdd(&sum[threadIdx.x],   lsum[threadIdx.x]);
        atomicAdd(&sumsq[threadIdx.x], lssq[threadIdx.x]);
    }
}

// ---------------- GEMM2: relu(bn(H0)) * W1^T -> H1 bf16 + column stats (BN fused in A-load) ----
__global__ __launch_bounds__(512) void gemm2_kernel(const bf16_t* __restrict__ A,
                                                    const bf16_t* __restrict__ Wt,
                                                    const float* __restrict__ scale,
                                                    const float* __restrict__ shift,
                                                    bf16_t* __restrict__ H,
                                                    float* __restrict__ sum,
                                                    float* __restrict__ sumsq) {
    const int K = M0;   // 256
    __shared__ float ssc[256], ssh[256];
    if (threadIdx.x < 256) { ssc[threadIdx.x] = scale[threadIdx.x]; ssh[threadIdx.x] = shift[threadIdx.x]; }
    __syncthreads();
    int wave = threadIdx.x >> 6;
    int lane = threadIdx.x & 63;
    int wr = wave >> 2, wc = wave & 3;
    int row0 = blockIdx.x * 128 + wr * 64;
    int col0 = wc * 64;
    int l15  = lane & 15;
    int quad = lane >> 4;
    f32x4 acc[4][4] = {};
    const bf16_t* Ap = A  + ((size_t)row0 + l15) * K + quad * 8;
    const bf16_t* Wp = Wt + ((size_t)col0 + l15) * K + quad * 8;
    for (int k0 = 0; k0 < K; k0 += 32) {
        int kb = k0 + quad * 8;
        float4 sc0 = *(const float4*)&ssc[kb], sc1 = *(const float4*)&ssc[kb + 4];
        float4 sh0 = *(const float4*)&ssh[kb], sh1 = *(const float4*)&ssh[kb + 4];
        bf16x8 a[4], bfr[4];
#pragma unroll
        for (int i = 0; i < 4; ++i) {
            bf16x8 raw = *(const bf16x8*)(Ap + (size_t)i * 16 * K + k0);
            bf16x8 t;
            t[0] = (bf16_t)fmaxf(fmaf((float)raw[0], sc0.x, sh0.x), 0.0f);
            t[1] = (bf16_t)fmaxf(fmaf((float)raw[1], sc0.y, sh0.y), 0.0f);
            t[2] = (bf16_t)fmaxf(fmaf((float)raw[2], sc0.z, sh0.z), 0.0f);
            t[3] = (bf16_t)fmaxf(fmaf((float)raw[3], sc0.w, sh0.w), 0.0f);
            t[4] = (bf16_t)fmaxf(fmaf((float)raw[4], sc1.x, sh1.x), 0.0f);
            t[5] = (bf16_t)fmaxf(fmaf((float)raw[5], sc1.y, sh1.y), 0.0f);
            t[6] = (bf16_t)fmaxf(fmaf((float)raw[6], sc1.z, sh1.z), 0.0f);
            t[7] = (bf16_t)fmaxf(fmaf((float)raw[7], sc1.w, sh1.w), 0.0f);
            a[i] = t;
        }
#pragma unroll
        for (int i = 0; i < 4; ++i) bfr[i] = *(const bf16x8*)(Wp + (size_t)i * 16 * K + k0);
#pragma unroll
        for (int mi = 0; mi < 4; ++mi)
#pragma unroll
            for (int ni = 0; ni < 4; ++ni)
                acc[mi][ni] = __builtin_amdgcn_mfma_f32_16x16x32_bf16(a[mi], bfr[ni], acc[mi][ni], 0, 0, 0);
    }
#pragma unroll
    for (int mi = 0; mi < 4; ++mi)
#pragma unroll
        for (int ni = 0; ni < 4; ++ni) {
            int col  = col0 + ni * 16 + l15;
            int rowb = row0 + mi * 16 + quad * 4;
#pragma unroll
            for (int r = 0; r < 4; ++r)
                H[(size_t)(rowb + r) * 256 + col] = (bf16_t)acc[mi][ni][r];
        }
    __shared__ float lsum[256], lssq[256];
    if (threadIdx.x < 256) { lsum[threadIdx.x] = 0.0f; lssq[threadIdx.x] = 0.0f; }
    __syncthreads();
#pragma unroll
    for (int ni = 0; ni < 4; ++ni) {
        float s = 0.0f, ss = 0.0f;
#pragma unroll
        for (int mi = 0; mi < 4; ++mi)
#pragma unroll
            for (int r = 0; r < 4; ++r) {
                float v = acc[mi][ni][r];
                s += v; ss = fmaf(v, v, ss);
            }
        s  += __shfl_xor(s, 16);  s  += __shfl_xor(s, 32);
        ss += __shfl_xor(ss, 16); ss += __shfl_xor(ss, 32);
        if (quad == 0) {
            int cl = col0 + ni * 16 + l15;
            atomicAdd(&lsum[cl], s);
            atomicAdd(&lssq[cl], ss);
        }
    }
    __syncthreads();
    if (threadIdx.x < 256) {
        atomicAdd(&sum[threadIdx.x],   lsum[threadIdx.x]);
        atomicAdd(&sumsq[threadIdx.x], lssq[threadIdx.x]);
    }
}

// ---------------- BN stats -> scale/shift ----------------
__global__ void finalize_kernel(const float* __restrict__ sum, const float* __restrict__ sumsq,
                                const float* __restrict__ gamma, const float* __restrict__ beta,
                                float* __restrict__ scale, float* __restrict__ shift) {
    int c = threadIdx.x;
    float m   = sum[c]   * (1.0f / NP);
    float var = sumsq[c] * (1.0f / NP) - m * m;
    float sc  = rsqrtf(var + 1e-5f) * gamma[c];
    scale[c] = sc;
    shift[c] = fmaf(-m, sc, beta[c]);
}

// ---------------- final BN+ReLU: H1 bf16 -> fp32 d_out ----------------
__global__ void bnrelu_final_kernel(const bf16_t* __restrict__ H, const float* __restrict__ scale,
                                    const float* __restrict__ shift, float* __restrict__ out) {
    int tid = blockIdx.x * 256 + threadIdx.x;   // one tid = 8 elements
    bf16x8 v = *(const bf16x8*)(H + (size_t)tid * 8);
    int c = (tid & 31) * 8;
    float4 o0, o1;
    o0.x = fmaxf(fmaf((float)v[0], scale[c + 0], shift[c + 0]), 0.0f);
    o0.y = fmaxf(fmaf((float)v[1], scale[c + 1], shift[c + 1]), 0.0f);
    o0.z = fmaxf(fmaf((float)v[2], scale[c + 2], shift[c + 2]), 0.0f);
    o0.w = fmaxf(fmaf((float)v[3], scale[c + 3], shift[c + 3]), 0.0f);
    o1.x = fmaxf(fmaf((float)v[4], scale[c + 4], shift[c + 4]), 0.0f);
    o1.y = fmaxf(fmaf((float)v[5], scale[c + 5], shift[c + 5]), 0.0f);
    o1.z = fmaxf(fmaf((float)v[6], scale[c + 6], shift[c + 6]), 0.0f);
    o1.w = fmaxf(fmaf((float)v[7], scale[c + 7], shift[c + 7]), 0.0f);
    ((float4*)out)[tid * 2]     = o0;
    ((float4*)out)[tid * 2 + 1] = o1;
}

extern "C" void kernel_launch(void* const* d_in, const int* in_sizes, int n_in,
                              void* d_out, int out_size, void* d_ws, size_t ws_size,
                              hipStream_t stream) {
    const float* xyz1    = (const float*)d_in[0];
    const float* xyz2    = (const float*)d_in[1];
    const float* points1 = (const float*)d_in[2];
    const float* points2 = (const float*)d_in[3];
    const float* W0      = (const float*)d_in[4];
    const float* g0      = (const float*)d_in[5];
    const float* b0      = (const float*)d_in[6];
    const float* W1      = (const float*)d_in[7];
    const float* g1      = (const float*)d_in[8];
    const float* b1      = (const float*)d_in[9];
    float* out = (float*)d_out;

    // ws layout (float offsets), total ~86 MB
    float* wsf    = (float*)d_ws;
    float* s0     = wsf + 0;
    float* ss0    = wsf + 256;
    float* s1     = wsf + 512;
    float* ss1    = wsf + 768;
    float* scale0 = wsf + 1024;
    float* shift0 = wsf + 1280;
    float* scale1 = wsf + 1536;
    float* shift1 = wsf + 1792;
    float* w3     = wsf + 2048;                       // 196608 f
    int*   idx3   = (int*)(wsf + 198656);             // 196608 i
    bf16_t* Wb0   = (bf16_t*)(wsf + 395264);          // 98304 bf16
    bf16_t* Wb1   = (bf16_t*)(wsf + 444416);          // 65536 bf16
    // X region [477184 .. 13060096): X (NP*384 bf16); pd/pi and later H1 alias it
    bf16_t* X     = (bf16_t*)(wsf + 477184);
    float* pd     = wsf + 477184;                     // NP*24 f (dead after merge)
    int*   pi     = (int*)(wsf + 2050048);
    bf16_t* H1    = (bf16_t*)(wsf + 477184);          // NP*256 bf16 (X dead after GEMM1)
    bf16_t* H0    = (bf16_t*)(wsf + 13060096);        // NP*256 bf16

    hipMemsetAsync(wsf, 0, 1024 * sizeof(float), stream);   // zero stat accumulators

    cvt_bf16_kernel<<<(M0 * CIN + 255) / 256, 256, 0, stream>>>(W0, Wb0, M0 * CIN);
    cvt_bf16_kernel<<<(M0 * M0 + 255) / 256, 256, 0, stream>>>(W1, Wb1, M0 * M0);

    nn3_partial_kernel<<<dim3(B_SZ * (N1 / 256), CHUNKS), 256, 0, stream>>>(xyz1, xyz2, pd, pi);
    nn3_merge_kernel<<<NP / 256, 256, 0, stream>>>(pd, pi, idx3, w3);
    gather_kernel<<<NP, 128, 0, stream>>>(points1, points2, idx3, w3, X);

    // layer 0: GEMM (+stats) -> H0 bf16; finalize scale/shift
    gemm1_kernel<<<NP / 128, 512, 0, stream>>>(X, Wb0, H0, s0, ss0);
    finalize_kernel<<<1, 256, 0, stream>>>(s0, ss0, g0, b0, scale0, shift0);

    // layer 1: GEMM with fused BN+ReLU on A (+stats) -> H1 bf16; finalize
    gemm2_kernel<<<NP / 128, 512, 0, stream>>>(H0, Wb1, scale0, shift0, H1, s1, ss1);
    finalize_kernel<<<1, 256, 0, stream>>>(s1, ss1, g1, b1, scale1, shift1);

    // final BN+ReLU -> fp32 output
    bnrelu_final_kernel<<<NP * 256 / 8 / 256, 256, 0, stream>>>(H1, scale1, shift1, out);
}

// Round 4
// 313.456 us; speedup vs baseline: 2.1803x; 1.1882x over previous
//
#include <hip/hip_runtime.h>

#define B_SZ 8
#define N1 8192
#define N2 2048
#define C1 128
#define C2 256
#define CIN 384
#define M0 256
#define NP (B_SZ * N1)   // 65536
#define CHUNKS 8
#define CHUNK (N2 / CHUNKS)   // 256

typedef __bf16 bf16_t;
typedef bf16_t bf16x8 __attribute__((ext_vector_type(8)));
typedef bf16_t bf16x4 __attribute__((ext_vector_type(4)));
typedef bf16_t bf16x2 __attribute__((ext_vector_type(2)));
typedef float  f32x4  __attribute__((ext_vector_type(4)));

// ---------------- fp32 -> bf16 weight convert ----------------
__global__ void cvt_bf16_kernel(const float* __restrict__ in, bf16_t* __restrict__ out, int n) {
    int i = blockIdx.x * 256 + threadIdx.x;
    if (i < n) out[i] = (bf16_t)in[i];
}

// ---------------- 3-NN partial: SQUARED-distance compare (no sqrt in inner loop) --------
// grid: dim3(B*N1/256, CHUNKS) = 2048 blocks; block = 256 queries x 256-candidate chunk.
// Top-3 by sq == top-3 by sqrt(sq) (monotone); sqrt applied to survivors in merge.
__global__ __launch_bounds__(256) void nn3_partial_kernel(const float* __restrict__ xyz1,
                                                          const float* __restrict__ xyz2,
                                                          float* __restrict__ pd,
                                                          int* __restrict__ pi) {
    __shared__ float4 s2[CHUNK];   // 4 KB: x,y,z,|p|^2
    int b = blockIdx.x >> 5;
    int i = ((blockIdx.x & 31) << 8) + threadIdx.x;
    int c = blockIdx.y;
    const float* x2 = xyz2 + ((size_t)b * N2 + (size_t)c * CHUNK) * 3;
    {
        int j = threadIdx.x;
        float x = x2[j * 3 + 0], y = x2[j * 3 + 1], z = x2[j * 3 + 2];
        s2[j] = make_float4(x, y, z, x * x + y * y + z * z);
    }
    __syncthreads();
    const float* p = xyz1 + ((size_t)b * N1 + i) * 3;
    float px = p[0], py = p[1], pz = p[2];
    float pn = px * px + py * py + pz * pz;
    float d0 = 1e30f, d1 = 1e30f, d2 = 1e30f;   // squared distances
    int   j0 = 0,     j1 = 0,     j2 = 0;
#pragma unroll 4
    for (int j = 0; j < CHUNK; ++j) {
        float4 v = s2[j];
        float dot = fmaf(px, v.x, fmaf(py, v.y, pz * v.z));
        float sq  = fmaf(-2.0f, dot, pn + v.w);   // no sqrt, no clamp: order-preserving
        bool c0 = sq < d0, c1 = sq < d1, c2 = sq < d2;
        d2 = c1 ? d1 : (c2 ? sq : d2);
        j2 = c1 ? j1 : (c2 ? j  : j2);
        d1 = c0 ? d0 : (c1 ? sq : d1);
        j1 = c0 ? j0 : (c1 ? j  : j1);
        d0 = c0 ? sq : d0;
        j0 = c0 ? j  : j0;
    }
    int jb = c * CHUNK;
    size_t o = (((size_t)b * N1 + i) * CHUNKS + (size_t)c) * 3;
    pd[o] = d0; pd[o + 1] = d1; pd[o + 2] = d2;
    pi[o] = j0 + jb; pi[o + 1] = j1 + jb; pi[o + 2] = j2 + jb;
}

// ---------------- merge 8 partial top-3 (by sq), then sqrt + weights ----------------
__global__ void nn3_merge_kernel(const float* __restrict__ pd, const int* __restrict__ pi,
                                 int* __restrict__ idx3, float* __restrict__ w3) {
    int p = blockIdx.x * 256 + threadIdx.x;
    const float* dp = pd + (size_t)p * (CHUNKS * 3);
    const int*   ip = pi + (size_t)p * (CHUNKS * 3);
    float d0 = 1e30f, d1 = 1e30f, d2 = 1e30f;
    int   j0 = 0,     j1 = 0,     j2 = 0;
#pragma unroll
    for (int k = 0; k < CHUNKS * 3; ++k) {
        float d = dp[k];
        int   j = ip[k];
        bool c0 = d < d0, c1 = d < d1, c2 = d < d2;
        d2 = c1 ? d1 : (c2 ? d : d2);
        j2 = c1 ? j1 : (c2 ? j : j2);
        d1 = c0 ? d0 : (c1 ? d : d1);
        j1 = c0 ? j0 : (c1 ? j : j1);
        d0 = c0 ? d : d0;
        j0 = c0 ? j : j0;
    }
    // reference semantics: d = sqrt(max(sq,0)); w = (1/(d+1e-8)) normalized
    float r0 = sqrtf(fmaxf(d0, 0.0f));
    float r1 = sqrtf(fmaxf(d1, 0.0f));
    float r2 = sqrtf(fmaxf(d2, 0.0f));
    float inv0 = 1.0f / (r0 + 1e-8f);
    float inv1 = 1.0f / (r1 + 1e-8f);
    float inv2 = 1.0f / (r2 + 1e-8f);
    float s = inv0 + inv1 + inv2;
    size_t o = (size_t)p * 3;
    w3[o] = inv0 / s; w3[o + 1] = inv1 / s; w3[o + 2] = inv2 / s;
    idx3[o] = j0; idx3[o + 1] = j1; idx3[o + 2] = j2;
}

// ---------------- gather + weighted sum + concat -> X bf16 ----------------
// 256-thr block = 2 points (halves block-dispatch count vs 128-thr/point).
__global__ __launch_bounds__(256) void gather_kernel(const float* __restrict__ points1,
                                                     const float* __restrict__ points2,
                                                     const int* __restrict__ idx3,
                                                     const float* __restrict__ w3,
                                                     bf16_t* __restrict__ X) {
    int p = blockIdx.x * 2 + (threadIdx.x >> 7);
    int t = threadIdx.x & 127;
    int b = p >> 13;
    const int*   id = idx3 + (size_t)p * 3;
    const float* w  = w3  + (size_t)p * 3;
    int   i0 = id[0], i1 = id[1], i2 = id[2];
    float w0 = w[0],  w1 = w[1],  w2 = w[2];
    const float* P2 = points2 + (size_t)b * N2 * C2;
    bf16_t* Xr = X + (size_t)p * CIN;
    if (t < 64) {
        int c = t * 4;
        float4 a  = *(const float4*)(P2 + (size_t)i0 * C2 + c);
        float4 bb = *(const float4*)(P2 + (size_t)i1 * C2 + c);
        float4 cc = *(const float4*)(P2 + (size_t)i2 * C2 + c);
        bf16x4 o;
        o[0] = (bf16_t)(w0 * a.x + w1 * bb.x + w2 * cc.x);
        o[1] = (bf16_t)(w0 * a.y + w1 * bb.y + w2 * cc.y);
        o[2] = (bf16_t)(w0 * a.z + w1 * bb.z + w2 * cc.z);
        o[3] = (bf16_t)(w0 * a.w + w1 * bb.w + w2 * cc.w);
        *(bf16x4*)(Xr + c) = o;
    } else {
        int c = (t - 64) * 2;
        float2 v = *(const float2*)(points1 + (size_t)p * C1 + c);
        bf16x2 o;
        o[0] = (bf16_t)v.x; o[1] = (bf16_t)v.y;
        *(bf16x2*)(Xr + C2 + c) = o;
    }
}

// ---------------- GEMM1: X(NP x 384) * W0^T -> H0 bf16 (NP x 256) + column stats ----------------
// 512 thr = 8 waves (2 row x 4 col), block tile 128x256, wave tile 64x64.
__global__ __launch_bounds__(512) void gemm1_kernel(const bf16_t* __restrict__ A,
                                                    const bf16_t* __restrict__ Wt,
                                                    bf16_t* __restrict__ H,
                                                    float* __restrict__ sum,
                                                    float* __restrict__ sumsq) {
    const int K = CIN;
    int wave = threadIdx.x >> 6;
    int lane = threadIdx.x & 63;
    int wr = wave >> 2, wc = wave & 3;
    int row0 = blockIdx.x * 128 + wr * 64;
    int col0 = wc * 64;
    int l15  = lane & 15;
    int quad = lane >> 4;
    f32x4 acc[4][4] = {};
    const bf16_t* Ap = A  + ((size_t)row0 + l15) * K + quad * 8;
    const bf16_t* Wp = Wt + ((size_t)col0 + l15) * K + quad * 8;
    for (int k0 = 0; k0 < K; k0 += 32) {
        bf16x8 a[4], bfr[4];
#pragma unroll
        for (int i = 0; i < 4; ++i) a[i]   = *(const bf16x8*)(Ap + (size_t)i * 16 * K + k0);
#pragma unroll
        for (int i = 0; i < 4; ++i) bfr[i] = *(const bf16x8*)(Wp + (size_t)i * 16 * K + k0);
#pragma unroll
        for (int mi = 0; mi < 4; ++mi)
#pragma unroll
            for (int ni = 0; ni < 4; ++ni)
                acc[mi][ni] = __builtin_amdgcn_mfma_f32_16x16x32_bf16(a[mi], bfr[ni], acc[mi][ni], 0, 0, 0);
    }
    // C/D layout (verified m89): col = lane&15, row = quad*4 + reg
#pragma unroll
    for (int mi = 0; mi < 4; ++mi)
#pragma unroll
        for (int ni = 0; ni < 4; ++ni) {
            int col  = col0 + ni * 16 + l15;
            int rowb = row0 + mi * 16 + quad * 4;
#pragma unroll
            for (int r = 0; r < 4; ++r)
                H[(size_t)(rowb + r) * 256 + col] = (bf16_t)acc[mi][ni][r];
        }
    __shared__ float lsum[256], lssq[256];
    if (threadIdx.x < 256) { lsum[threadIdx.x] = 0.0f; lssq[threadIdx.x] = 0.0f; }
    __syncthreads();
#pragma unroll
    for (int ni = 0; ni < 4; ++ni) {
        float s = 0.0f, ss = 0.0f;
#pragma unroll
        for (int mi = 0; mi < 4; ++mi)
#pragma unroll
            for (int r = 0; r < 4; ++r) {
                float v = acc[mi][ni][r];
                s += v; ss = fmaf(v, v, ss);
            }
        s  += __shfl_xor(s, 16);  s  += __shfl_xor(s, 32);
        ss += __shfl_xor(ss, 16); ss += __shfl_xor(ss, 32);
        if (quad == 0) {
            int cl = col0 + ni * 16 + l15;
            atomicAdd(&lsum[cl], s);
            atomicAdd(&lssq[cl], ss);
        }
    }
    __syncthreads();
    if (threadIdx.x < 256) {
        atomicAdd(&sum[threadIdx.x],   lsum[threadIdx.x]);
        atomicAdd(&sumsq[threadIdx.x], lssq[threadIdx.x]);
    }
}

// ---------------- GEMM2: relu(bn(H0)) * W1^T -> H1 bf16 + column stats (BN fused in A-load) ----
__global__ __launch_bounds__(512) void gemm2_kernel(const bf16_t* __restrict__ A,
                                                    const bf16_t* __restrict__ Wt,
                                                    const float* __restrict__ scale,
                                                    const float* __restrict__ shift,
                                                    bf16_t* __restrict__ H,
                                                    float* __restrict__ sum,
                                                    float* __restrict__ sumsq) {
    const int K = M0;   // 256
    __shared__ float ssc[256], ssh[256];
    if (threadIdx.x < 256) { ssc[threadIdx.x] = scale[threadIdx.x]; ssh[threadIdx.x] = shift[threadIdx.x]; }
    __syncthreads();
    int wave = threadIdx.x >> 6;
    int lane = threadIdx.x & 63;
    int wr = wave >> 2, wc = wave & 3;
    int row0 = blockIdx.x * 128 + wr * 64;
    int col0 = wc * 64;
    int l15  = lane & 15;
    int quad = lane >> 4;
    f32x4 acc[4][4] = {};
    const bf16_t* Ap = A  + ((size_t)row0 + l15) * K + quad * 8;
    const bf16_t* Wp = Wt + ((size_t)col0 + l15) * K + quad * 8;
    for (int k0 = 0; k0 < K; k0 += 32) {
        int kb = k0 + quad * 8;
        float4 sc0 = *(const float4*)&ssc[kb], sc1 = *(const float4*)&ssc[kb + 4];
        float4 sh0 = *(const float4*)&ssh[kb], sh1 = *(const float4*)&ssh[kb + 4];
        bf16x8 a[4], bfr[4];
#pragma unroll
        for (int i = 0; i < 4; ++i) {
            bf16x8 raw = *(const bf16x8*)(Ap + (size_t)i * 16 * K + k0);
            bf16x8 t;
            t[0] = (bf16_t)fmaxf(fmaf((float)raw[0], sc0.x, sh0.x), 0.0f);
            t[1] = (bf16_t)fmaxf(fmaf((float)raw[1], sc0.y, sh0.y), 0.0f);
            t[2] = (bf16_t)fmaxf(fmaf((float)raw[2], sc0.z, sh0.z), 0.0f);
            t[3] = (bf16_t)fmaxf(fmaf((float)raw[3], sc0.w, sh0.w), 0.0f);
            t[4] = (bf16_t)fmaxf(fmaf((float)raw[4], sc1.x, sh1.x), 0.0f);
            t[5] = (bf16_t)fmaxf(fmaf((float)raw[5], sc1.y, sh1.y), 0.0f);
            t[6] = (bf16_t)fmaxf(fmaf((float)raw[6], sc1.z, sh1.z), 0.0f);
            t[7] = (bf16_t)fmaxf(fmaf((float)raw[7], sc1.w, sh1.w), 0.0f);
            a[i] = t;
        }
#pragma unroll
        for (int i = 0; i < 4; ++i) bfr[i] = *(const bf16x8*)(Wp + (size_t)i * 16 * K + k0);
#pragma unroll
        for (int mi = 0; mi < 4; ++mi)
#pragma unroll
            for (int ni = 0; ni < 4; ++ni)
                acc[mi][ni] = __builtin_amdgcn_mfma_f32_16x16x32_bf16(a[mi], bfr[ni], acc[mi][ni], 0, 0, 0);
    }
#pragma unroll
    for (int mi = 0; mi < 4; ++mi)
#pragma unroll
        for (int ni = 0; ni < 4; ++ni) {
            int col  = col0 + ni * 16 + l15;
            int rowb = row0 + mi * 16 + quad * 4;
#pragma unroll
            for (int r = 0; r < 4; ++r)
                H[(size_t)(rowb + r) * 256 + col] = (bf16_t)acc[mi][ni][r];
        }
    __shared__ float lsum[256], lssq[256];
    if (threadIdx.x < 256) { lsum[threadIdx.x] = 0.0f; lssq[threadIdx.x] = 0.0f; }
    __syncthreads();
#pragma unroll
    for (int ni = 0; ni < 4; ++ni) {
        float s = 0.0f, ss = 0.0f;
#pragma unroll
        for (int mi = 0; mi < 4; ++mi)
#pragma unroll
            for (int r = 0; r < 4; ++r) {
                float v = acc[mi][ni][r];
                s += v; ss = fmaf(v, v, ss);
            }
        s  += __shfl_xor(s, 16);  s  += __shfl_xor(s, 32);
        ss += __shfl_xor(ss, 16); ss += __shfl_xor(ss, 32);
        if (quad == 0) {
            int cl = col0 + ni * 16 + l15;
            atomicAdd(&lsum[cl], s);
            atomicAdd(&lssq[cl], ss);
        }
    }
    __syncthreads();
    if (threadIdx.x < 256) {
        atomicAdd(&sum[threadIdx.x],   lsum[threadIdx.x]);
        atomicAdd(&sumsq[threadIdx.x], lssq[threadIdx.x]);
    }
}

// ---------------- BN stats -> scale/shift ----------------
__global__ void finalize_kernel(const float* __restrict__ sum, const float* __restrict__ sumsq,
                                const float* __restrict__ gamma, const float* __restrict__ beta,
                                float* __restrict__ scale, float* __restrict__ shift) {
    int c = threadIdx.x;
    float m   = sum[c]   * (1.0f / NP);
    float var = sumsq[c] * (1.0f / NP) - m * m;
    float sc  = rsqrtf(var + 1e-5f) * gamma[c];
    scale[c] = sc;
    shift[c] = fmaf(-m, sc, beta[c]);
}

// ---------------- final BN+ReLU: H1 bf16 -> fp32 d_out ----------------
__global__ void bnrelu_final_kernel(const bf16_t* __restrict__ H, const float* __restrict__ scale,
                                    const float* __restrict__ shift, float* __restrict__ out) {
    int tid = blockIdx.x * 256 + threadIdx.x;   // one tid = 8 elements
    bf16x8 v = *(const bf16x8*)(H + (size_t)tid * 8);
    int c = (tid & 31) * 8;
    float4 o0, o1;
    o0.x = fmaxf(fmaf((float)v[0], scale[c + 0], shift[c + 0]), 0.0f);
    o0.y = fmaxf(fmaf((float)v[1], scale[c + 1], shift[c + 1]), 0.0f);
    o0.z = fmaxf(fmaf((float)v[2], scale[c + 2], shift[c + 2]), 0.0f);
    o0.w = fmaxf(fmaf((float)v[3], scale[c + 3], shift[c + 3]), 0.0f);
    o1.x = fmaxf(fmaf((float)v[4], scale[c + 4], shift[c + 4]), 0.0f);
    o1.y = fmaxf(fmaf((float)v[5], scale[c + 5], shift[c + 5]), 0.0f);
    o1.z = fmaxf(fmaf((float)v[6], scale[c + 6], shift[c + 6]), 0.0f);
    o1.w = fmaxf(fmaf((float)v[7], scale[c + 7], shift[c + 7]), 0.0f);
    ((float4*)out)[tid * 2]     = o0;
    ((float4*)out)[tid * 2 + 1] = o1;
}

extern "C" void kernel_launch(void* const* d_in, const int* in_sizes, int n_in,
                              void* d_out, int out_size, void* d_ws, size_t ws_size,
                              hipStream_t stream) {
    const float* xyz1    = (const float*)d_in[0];
    const float* xyz2    = (const float*)d_in[1];
    const float* points1 = (const float*)d_in[2];
    const float* points2 = (const float*)d_in[3];
    const float* W0      = (const float*)d_in[4];
    const float* g0      = (const float*)d_in[5];
    const float* b0      = (const float*)d_in[6];
    const float* W1      = (const float*)d_in[7];
    const float* g1      = (const float*)d_in[8];
    const float* b1      = (const float*)d_in[9];
    float* out = (float*)d_out;

    // ws layout (float offsets), total ~86 MB
    float* wsf    = (float*)d_ws;
    float* s0     = wsf + 0;
    float* ss0    = wsf + 256;
    float* s1     = wsf + 512;
    float* ss1    = wsf + 768;
    float* scale0 = wsf + 1024;
    float* shift0 = wsf + 1280;
    float* scale1 = wsf + 1536;
    float* shift1 = wsf + 1792;
    float* w3     = wsf + 2048;                       // 196608 f
    int*   idx3   = (int*)(wsf + 198656);             // 196608 i
    bf16_t* Wb0   = (bf16_t*)(wsf + 395264);          // 98304 bf16
    bf16_t* Wb1   = (bf16_t*)(wsf + 444416);          // 65536 bf16
    // X region [477184 .. 13060096): X (NP*384 bf16); pd/pi and later H1 alias it
    bf16_t* X     = (bf16_t*)(wsf + 477184);
    float* pd     = wsf + 477184;                     // NP*24 f (dead after merge)
    int*   pi     = (int*)(wsf + 2050048);
    bf16_t* H1    = (bf16_t*)(wsf + 477184);          // NP*256 bf16 (X dead after GEMM1)
    bf16_t* H0    = (bf16_t*)(wsf + 13060096);        // NP*256 bf16

    hipMemsetAsync(wsf, 0, 1024 * sizeof(float), stream);   // zero stat accumulators

    cvt_bf16_kernel<<<(M0 * CIN + 255) / 256, 256, 0, stream>>>(W0, Wb0, M0 * CIN);
    cvt_bf16_kernel<<<(M0 * M0 + 255) / 256, 256, 0, stream>>>(W1, Wb1, M0 * M0);

    nn3_partial_kernel<<<dim3(B_SZ * (N1 / 256), CHUNKS), 256, 0, stream>>>(xyz1, xyz2, pd, pi);
    nn3_merge_kernel<<<NP / 256, 256, 0, stream>>>(pd, pi, idx3, w3);
    gather_kernel<<<NP / 2, 256, 0, stream>>>(points1, points2, idx3, w3, X);

    // layer 0: GEMM (+stats) -> H0 bf16; finalize scale/shift
    gemm1_kernel<<<NP / 128, 512, 0, stream>>>(X, Wb0, H0, s0, ss0);
    finalize_kernel<<<1, 256, 0, stream>>>(s0, ss0, g0, b0, scale0, shift0);

    // layer 1: GEMM with fused BN+ReLU on A (+stats) -> H1 bf16; finalize
    gemm2_kernel<<<NP / 128, 512, 0, stream>>>(H0, Wb1, scale0, shift0, H1, s1, ss1);
    finalize_kernel<<<1, 256, 0, stream>>>(s1, ss1, g1, b1, scale1, shift1);

    // final BN+ReLU -> fp32 output
    bnrelu_final_kernel<<<NP * 256 / 8 / 256, 256, 0, stream>>>(H1, scale1, shift1, out);
}